// Round 2
// baseline (549.156 us; speedup 1.0000x reference)
//
#include <hip/hip_runtime.h>
#include <math.h>

// Problem constants: B=8, S=4096, D=1024, Q=16  -> 32768 rows
#define ROWS_TOTAL 32768
#define DDIM 1024
#define QDIM 16

// ===========================================================================
// Pass 1: z[r][q] = cos(relu(x[r]·W1[:,q] + b1[q]) + theta[q])
//
// Wave-independent, zero-LDS, zero-barrier. Lane layout within a wave:
//   kh = lane>>5      (which 512-wide half of k this lane sums)
//   rr = (lane>>2)&7  (which of the wave's 8 rows)
//   qg = lane&3       (which q-quad: q = 4qg..4qg+3)
// Each lane serially accumulates 512 k-terms for 4 q's (4 independent FMA
// chains). W1 is [D][Q] so W1[k][4qg..+3] is a float4 (8-fold rr-broadcast);
// x[r][k..k+3] is a float4 (4-fold qg-broadcast). End: one shfl_xor(32) per
// component merges the two k-halves. No cross-wave anything.
// ===========================================================================
#define K1_TPB 256
#define K1_ROWS_PER_WAVE 8
#define K1_NBLOCKS (ROWS_TOTAL / (K1_ROWS_PER_WAVE * (K1_TPB / 64)))  // 1024

__global__ __launch_bounds__(K1_TPB, 4)
void qz_kernel(const float* __restrict__ x, const float* __restrict__ W1,
               const float* __restrict__ b1, const float* __restrict__ theta,
               float* __restrict__ z) {
  const int lane = threadIdx.x & 63;
  const int wv = blockIdx.x * (K1_TPB / 64) + (threadIdx.x >> 6);
  const int kh = lane >> 5;
  const int rr = (lane >> 2) & 7;
  const int qg = lane & 3;
  const int row = wv * K1_ROWS_PER_WAVE + rr;

  const float* xp = x + (size_t)row * DDIM + kh * (DDIM / 2);
  const float* wp = W1 + (size_t)(kh * (DDIM / 2)) * QDIM + 4 * qg;

  float4 acc = make_float4(0.f, 0.f, 0.f, 0.f);

  // 64 stages of 8 k each. W1 double-buffered (distance ~2 stages, L1/L2-hot
  // since every wave re-reads the same 64 KB); x 4-deep pipelined (distance
  // 4 stages ~500 cyc to cover L3/HBM latency). All buffers statically
  // indexed (runtime-indexed arrays would go to scratch). Lambdas, NOT
  // macros: a macro parameter named 'w' would substitute into '.w' member
  // accesses (the R0 compile failure).
  float4 wA[8], wB[8];
  float4 x0[2], x1[2], x2[2], x3[2];

  auto loadw = [&](float4* wdst, int s) {
    const float* p = wp + (size_t)(s & 63) * (8 * QDIM);
#pragma unroll
    for (int j = 0; j < 8; ++j)
      wdst[j] = *reinterpret_cast<const float4*>(p + j * QDIM);
  };
  auto loadx = [&](float4* xdst, int s) {
    const float* p = xp + (s & 63) * 8;
    xdst[0] = *reinterpret_cast<const float4*>(p);
    xdst[1] = *reinterpret_cast<const float4*>(p + 4);
  };
  auto fmas = [&](const float4* wv4, const float4* xv4) {
    const float xs[8] = {xv4[0].x, xv4[0].y, xv4[0].z, xv4[0].w,
                         xv4[1].x, xv4[1].y, xv4[1].z, xv4[1].w};
#pragma unroll
    for (int j = 0; j < 8; ++j) {
      acc.x = fmaf(xs[j], wv4[j].x, acc.x);
      acc.y = fmaf(xs[j], wv4[j].y, acc.y);
      acc.z = fmaf(xs[j], wv4[j].z, acc.z);
      acc.w = fmaf(xs[j], wv4[j].w, acc.w);
    }
  };

  loadx(x0, 0); loadx(x1, 1); loadx(x2, 2); loadx(x3, 3);
  loadw(wA, 0); loadw(wB, 1);

#pragma unroll 1
  for (int it = 0; it < 64; it += 4) {
    fmas(wA, x0); loadx(x0, it + 4); loadw(wA, it + 2);
    fmas(wB, x1); loadx(x1, it + 5); loadw(wB, it + 3);
    fmas(wA, x2); loadx(x2, it + 6); loadw(wA, it + 4);
    fmas(wB, x3); loadx(x3, it + 7); loadw(wB, it + 5);
  }

  // merge the two k-halves (lane ^ 32); the only cross-lane traffic.
  const float hx = acc.x + __shfl_xor(acc.x, 32);
  const float hy = acc.y + __shfl_xor(acc.y, 32);
  const float hz = acc.z + __shfl_xor(acc.z, 32);
  const float hw = acc.w + __shfl_xor(acc.w, 32);

  if (lane < 32) {
    const float4 b1v = *reinterpret_cast<const float4*>(b1 + 4 * qg);
    const float4 thv = *reinterpret_cast<const float4*>(theta + 4 * qg);
    float4 zv;
    zv.x = __cosf(fmaxf(hx + b1v.x, 0.f) + thv.x);
    zv.y = __cosf(fmaxf(hy + b1v.y, 0.f) + thv.y);
    zv.z = __cosf(fmaxf(hz + b1v.z, 0.f) + thv.z);
    zv.w = __cosf(fmaxf(hw + b1v.w, 0.f) + thv.w);
    // lanes 0..31 = 8 rows x 4 quads -> one fully-coalesced 512B store
    *reinterpret_cast<float4*>(z + (size_t)row * QDIM + 4 * qg) = zv;
  }
}

// ===========================================================================
// Pass 2: out[r][d] = b2[d] + sum_q z[r][q] * W2[q][d]
// Thread owns 4 output columns (d = 4t..4t+3); W2[16][4] lives in 64 VGPRs,
// loaded once per block. Per row: 4 broadcast float4 z-loads (z is 2 MB,
// L2-resident) + 64 FMA + one coalesced float4 store. Zero LDS, no barriers.
// ===========================================================================
#define K2_TPB 256
#define K2_ROWS 16
#define K2_NBLOCKS (ROWS_TOTAL / K2_ROWS)  // 2048

__global__ __launch_bounds__(K2_TPB, 4)
void out_kernel(const float* __restrict__ z, const float* __restrict__ W2,
                const float* __restrict__ b2, float* __restrict__ out) {
  const int t = threadIdx.x;

  float4 w2r[QDIM];
#pragma unroll
  for (int q = 0; q < QDIM; ++q)
    w2r[q] = *reinterpret_cast<const float4*>(W2 + (size_t)q * DDIM + 4 * t);
  const float4 b2v = *reinterpret_cast<const float4*>(b2 + 4 * t);

  const int r0 = blockIdx.x * K2_ROWS;
  const float* zp = z + (size_t)r0 * QDIM;

  float4 zA[4], zB[4];
#pragma unroll
  for (int j = 0; j < 4; ++j)
    zA[j] = *reinterpret_cast<const float4*>(zp + 4 * j);

#pragma unroll
  for (int i = 0; i < K2_ROWS; ++i) {
    // static ping-pong (loop fully unrolled -> compile-time selection)
    float4* cur = (i & 1) ? zB : zA;
    float4* nxt = (i & 1) ? zA : zB;
    if (i + 1 < K2_ROWS) {
      const float* p = zp + (size_t)(i + 1) * QDIM;
#pragma unroll
      for (int j = 0; j < 4; ++j)
        nxt[j] = *reinterpret_cast<const float4*>(p + 4 * j);
    }
    float4 a = b2v;
#pragma unroll
    for (int j = 0; j < 4; ++j) {
      const float4 zv = cur[j];
      a.x = fmaf(zv.x, w2r[4 * j + 0].x, a.x);
      a.y = fmaf(zv.x, w2r[4 * j + 0].y, a.y);
      a.z = fmaf(zv.x, w2r[4 * j + 0].z, a.z);
      a.w = fmaf(zv.x, w2r[4 * j + 0].w, a.w);
      a.x = fmaf(zv.y, w2r[4 * j + 1].x, a.x);
      a.y = fmaf(zv.y, w2r[4 * j + 1].y, a.y);
      a.z = fmaf(zv.y, w2r[4 * j + 1].z, a.z);
      a.w = fmaf(zv.y, w2r[4 * j + 1].w, a.w);
      a.x = fmaf(zv.z, w2r[4 * j + 2].x, a.x);
      a.y = fmaf(zv.z, w2r[4 * j + 2].y, a.y);
      a.z = fmaf(zv.z, w2r[4 * j + 2].z, a.z);
      a.w = fmaf(zv.z, w2r[4 * j + 2].w, a.w);
      a.x = fmaf(zv.w, w2r[4 * j + 3].x, a.x);
      a.y = fmaf(zv.w, w2r[4 * j + 3].y, a.y);
      a.z = fmaf(zv.w, w2r[4 * j + 3].z, a.z);
      a.w = fmaf(zv.w, w2r[4 * j + 3].w, a.w);
    }
    *reinterpret_cast<float4*>(out + (size_t)(r0 + i) * DDIM + 4 * t) = a;
  }
}

// ===========================================================================
// Fallback: previous best fused kernel (used only if ws_size < 2 MB).
// ===========================================================================
#define TPB 512
#define RPB 16
#define R 4
#define NPH (RPB / R)
#define NBLOCKS (ROWS_TOTAL / RPB)

__global__ __launch_bounds__(TPB, 4)
void ffq_kernel(const float* __restrict__ x, const float* __restrict__ W1,
                const float* __restrict__ b1, const float* __restrict__ theta,
                const float* __restrict__ W2, const float* __restrict__ b2,
                float* __restrict__ out) {
  const int t    = threadIdx.x;
  const int lane = t & 63;
  const int wid  = t >> 6;
  const int qg   = t & 3;
  const int c    = t >> 2;
  const int q5   = lane & 15;
  const int r5   = lane >> 4;

  __shared__ __align__(16) float hw[2][16][R][QDIM];
  __shared__ __align__(16) float zs[8][R][QDIM];

  float w1r[8][4];
  {
    const float* p = W1 + (size_t)(8 * c) * QDIM + 4 * qg;
#pragma unroll
    for (int j = 0; j < 8; ++j) {
      float4 v = *reinterpret_cast<const float4*>(p + (size_t)j * QDIM);
      w1r[j][0] = v.x; w1r[j][1] = v.y; w1r[j][2] = v.z; w1r[j][3] = v.w;
    }
  }
  float w2r[QDIM][2];
#pragma unroll
  for (int q = 0; q < QDIM; ++q) {
    float2 v = *reinterpret_cast<const float2*>(W2 + (size_t)q * DDIM + 2 * t);
    w2r[q][0] = v.x; w2r[q][1] = v.y;
  }
  const float2 b2r = *reinterpret_cast<const float2*>(b2 + 2 * t);
  const float b1q = b1[q5];
  const float thq = theta[q5];

  const int row0 = blockIdx.x * RPB;

  float4 xa[R], xb[R];
  {
    const float* p = x + (size_t)row0 * DDIM + 8 * c;
#pragma unroll
    for (int r = 0; r < R; ++r) {
      xa[r] = *reinterpret_cast<const float4*>(p + (size_t)r * DDIM);
      xb[r] = *reinterpret_cast<const float4*>(p + (size_t)r * DDIM + 4);
    }
  }

  auto mm2_store = [&](int rowp) {
#pragma unroll
    for (int r = 0; r < R; ++r) {
      float o0 = b2r.x, o1 = b2r.y;
#pragma unroll
      for (int jb = 0; jb < 4; ++jb) {
        float4 zv = *reinterpret_cast<const float4*>(&zs[wid][r][4 * jb]);
        o0 = fmaf(zv.x, w2r[4 * jb + 0][0], o0);
        o1 = fmaf(zv.x, w2r[4 * jb + 0][1], o1);
        o0 = fmaf(zv.y, w2r[4 * jb + 1][0], o0);
        o1 = fmaf(zv.y, w2r[4 * jb + 1][1], o1);
        o0 = fmaf(zv.z, w2r[4 * jb + 2][0], o0);
        o1 = fmaf(zv.z, w2r[4 * jb + 2][1], o1);
        o0 = fmaf(zv.w, w2r[4 * jb + 3][0], o0);
        o1 = fmaf(zv.w, w2r[4 * jb + 3][1], o1);
      }
      *reinterpret_cast<float2*>(out + (size_t)(rowp + r) * DDIM + 2 * t) =
          make_float2(o0, o1);
    }
  };

  for (int ph = 0; ph < NPH; ++ph) {
    const int buf = ph & 1;

    float hp[R][4];
#pragma unroll
    for (int r = 0; r < R; ++r) {
      const float xv[8] = {xa[r].x, xa[r].y, xa[r].z, xa[r].w,
                           xb[r].x, xb[r].y, xb[r].z, xb[r].w};
      float h0 = 0.f, h1 = 0.f, h2 = 0.f, h3 = 0.f;
#pragma unroll
      for (int j = 0; j < 8; ++j) {
        h0 = fmaf(xv[j], w1r[j][0], h0);
        h1 = fmaf(xv[j], w1r[j][1], h1);
        h2 = fmaf(xv[j], w1r[j][2], h2);
        h3 = fmaf(xv[j], w1r[j][3], h3);
      }
      hp[r][0] = h0; hp[r][1] = h1; hp[r][2] = h2; hp[r][3] = h3;
    }

#pragma unroll
    for (int m = 4; m <= 16; m <<= 1)
#pragma unroll
      for (int r = 0; r < R; ++r)
#pragma unroll
        for (int qq = 0; qq < 4; ++qq)
          hp[r][qq] += __shfl_xor(hp[r][qq], m, 64);

    if ((lane & 28) == 0) {
      const int j = wid * 2 + (lane >> 5);
#pragma unroll
      for (int r = 0; r < R; ++r)
        *reinterpret_cast<float4*>(&hw[buf][j][r][4 * qg]) =
            make_float4(hp[r][0], hp[r][1], hp[r][2], hp[r][3]);
    }
    __syncthreads();

    if (ph + 1 < NPH) {
      const float* p = x + (size_t)(row0 + (ph + 1) * R) * DDIM + 8 * c;
#pragma unroll
      for (int r = 0; r < R; ++r) {
        xa[r] = *reinterpret_cast<const float4*>(p + (size_t)r * DDIM);
        xb[r] = *reinterpret_cast<const float4*>(p + (size_t)r * DDIM + 4);
      }
    }

    if (ph > 0) mm2_store(row0 + (ph - 1) * R);

    float s = 0.f;
#pragma unroll
    for (int j = 0; j < 16; ++j) s += hw[buf][j][r5][q5];
    s = fmaxf(s + b1q, 0.f) + thq;
    zs[wid][r5][q5] = __cosf(s);
  }

  __syncthreads();
  mm2_store(row0 + (NPH - 1) * R);
}

extern "C" void kernel_launch(void* const* d_in, const int* in_sizes, int n_in,
                              void* d_out, int out_size, void* d_ws, size_t ws_size,
                              hipStream_t stream) {
  const float* x     = (const float*)d_in[0];
  const float* W1    = (const float*)d_in[1];
  const float* b1    = (const float*)d_in[2];
  const float* theta = (const float*)d_in[3];
  const float* W2    = (const float*)d_in[4];
  const float* b2    = (const float*)d_in[5];
  float* out = (float*)d_out;

  const size_t z_bytes = (size_t)ROWS_TOTAL * QDIM * sizeof(float);  // 2 MiB
  if (ws_size >= z_bytes && d_ws != nullptr) {
    float* z = (float*)d_ws;
    qz_kernel<<<dim3(K1_NBLOCKS), dim3(K1_TPB), 0, stream>>>(x, W1, b1, theta, z);
    out_kernel<<<dim3(K2_NBLOCKS), dim3(K2_TPB), 0, stream>>>(z, W2, b2, out);
  } else {
    ffq_kernel<<<dim3(NBLOCKS), dim3(TPB), 0, stream>>>(x, W1, b1, theta, W2, b2, out);
  }
}

// Round 3
// 483.769 us; speedup vs baseline: 1.1352x; 1.1352x over previous
//
#include <hip/hip_runtime.h>
#include <math.h>

// Problem constants: B=8, S=4096, D=1024, Q=16  -> 32768 rows
#define ROWS_TOTAL 32768
#define DDIM 1024
#define QDIM 16

// ===========================================================================
// Pass 1: z[r][q] = cos(relu(x[r]·W1[:,q] + b1[q]) + theta[q])
//
// Lane layout (64 = 4 k-quarters x 4 row-pairs x 4 q-quads):
//   qg = lane&3        q = 4qg..4qg+3
//   rr = (lane>>2)&3   rows rowA=wv*8+2rr, rowB=rowA+1
//   kq = lane>>4       k-range [256*kq, 256*kq+256)
// Each lane: 2 rows x 4 q x 256 k serial FMA (one W1 float4 load feeds 8
// FMAs). k-quarters merged by shfl_xor(16)+shfl_xor(32) butterfly at the
// end. Zero LDS, zero barriers. ALL pipeline state in NAMED float4 scalars
// — R1's arrays-through-lambda-pointers were demoted to scratch (459 MB of
// HBM writes for a 2 MB output; VGPR_Count=64, VALUBusy 4%).
// ===========================================================================
#define K1_TPB 256
#define K1_NBLOCKS (ROWS_TOTAL / 8 / (K1_TPB / 64))  // 1024

__global__ __launch_bounds__(K1_TPB, 4)
void qz_kernel(const float* __restrict__ x, const float* __restrict__ W1,
               const float* __restrict__ b1, const float* __restrict__ theta,
               float* __restrict__ z) {
  const int lane = threadIdx.x & 63;
  const int wv = blockIdx.x * (K1_TPB / 64) + (threadIdx.x >> 6);
  const int qg = lane & 3;
  const int rr = (lane >> 2) & 3;
  const int kq = lane >> 4;
  const int rowA = wv * 8 + rr * 2;

  const float* xpA = x + (size_t)rowA * DDIM + kq * 256;
  const float* xpB = xpA + DDIM;  // rowA+1
  const float* wp = W1 + (size_t)(kq * 256) * QDIM + 4 * qg;

  float4 accA = make_float4(0.f, 0.f, 0.f, 0.f);
  float4 accB = make_float4(0.f, 0.f, 0.f, 0.f);

  // acc.c += xv.j * wj.c  (j = k-offset, c = q-offset) — 16 FMA per call.
  auto fma16 = [](float4& a, const float4 xv, const float4 w0, const float4 w1,
                  const float4 w2, const float4 w3) {
    a.x = fmaf(xv.x, w0.x, a.x); a.y = fmaf(xv.x, w0.y, a.y);
    a.z = fmaf(xv.x, w0.z, a.z); a.w = fmaf(xv.x, w0.w, a.w);
    a.x = fmaf(xv.y, w1.x, a.x); a.y = fmaf(xv.y, w1.y, a.y);
    a.z = fmaf(xv.y, w1.z, a.z); a.w = fmaf(xv.y, w1.w, a.w);
    a.x = fmaf(xv.z, w2.x, a.x); a.y = fmaf(xv.z, w2.y, a.y);
    a.z = fmaf(xv.z, w2.z, a.z); a.w = fmaf(xv.z, w2.w, a.w);
    a.x = fmaf(xv.w, w3.x, a.x); a.y = fmaf(xv.w, w3.y, a.y);
    a.z = fmaf(xv.w, w3.z, a.z); a.w = fmaf(xv.w, w3.w, a.w);
  };

  // prologue: x double-buffered (xa=even stage, xb=odd stage), W1 for stage 0
  float4 xaA = *reinterpret_cast<const float4*>(xpA);
  float4 xaB = *reinterpret_cast<const float4*>(xpB);
  float4 xbA = *reinterpret_cast<const float4*>(xpA + 4);
  float4 xbB = *reinterpret_cast<const float4*>(xpB + 4);
  float4 wa0 = *reinterpret_cast<const float4*>(wp + 0 * QDIM);
  float4 wa1 = *reinterpret_cast<const float4*>(wp + 1 * QDIM);
  float4 wa2 = *reinterpret_cast<const float4*>(wp + 2 * QDIM);
  float4 wa3 = *reinterpret_cast<const float4*>(wp + 3 * QDIM);

#pragma unroll 1
  for (int s = 0; s < 64; s += 2) {
    // W for odd stage s+1 (issued before even-stage FMAs -> latency hidden)
    const float* pwb = wp + (size_t)(4 * (s + 1)) * QDIM;
    const float4 wb0 = *reinterpret_cast<const float4*>(pwb + 0 * QDIM);
    const float4 wb1 = *reinterpret_cast<const float4*>(pwb + 1 * QDIM);
    const float4 wb2 = *reinterpret_cast<const float4*>(pwb + 2 * QDIM);
    const float4 wb3 = *reinterpret_cast<const float4*>(pwb + 3 * QDIM);

    // even stage s: consume xa / wa
    fma16(accA, xaA, wa0, wa1, wa2, wa3);
    fma16(accB, xaB, wa0, wa1, wa2, wa3);

    // prefetch x for stage s+2 (clamped on last iter; redundant re-read ok)
    const int sp = (s + 2 < 64) ? (s + 2) : 0;
    xaA = *reinterpret_cast<const float4*>(xpA + 4 * sp);
    xaB = *reinterpret_cast<const float4*>(xpB + 4 * sp);

    // W for even stage s+2
    const float* pwa = wp + (size_t)(4 * sp) * QDIM;
    wa0 = *reinterpret_cast<const float4*>(pwa + 0 * QDIM);
    wa1 = *reinterpret_cast<const float4*>(pwa + 1 * QDIM);
    wa2 = *reinterpret_cast<const float4*>(pwa + 2 * QDIM);
    wa3 = *reinterpret_cast<const float4*>(pwa + 3 * QDIM);

    // odd stage s+1: consume xb / wb
    fma16(accA, xbA, wb0, wb1, wb2, wb3);
    fma16(accB, xbB, wb0, wb1, wb2, wb3);

    // prefetch x for stage s+3
    const int sq = (s + 3 < 64) ? (s + 3) : 1;
    xbA = *reinterpret_cast<const float4*>(xpA + 4 * sq);
    xbB = *reinterpret_cast<const float4*>(xpB + 4 * sq);
  }

  // merge the 4 k-quarters: butterfly over lane bits 4 and 5
  auto red = [](float v) {
    v += __shfl_xor(v, 16);
    v += __shfl_xor(v, 32);
    return v;
  };
  accA.x = red(accA.x); accA.y = red(accA.y);
  accA.z = red(accA.z); accA.w = red(accA.w);
  accB.x = red(accB.x); accB.y = red(accB.y);
  accB.z = red(accB.z); accB.w = red(accB.w);

  // kq==0 lanes store rowA's quad, kq==1 lanes store rowB's quad
  if (kq < 2) {
    const float4 b1v = *reinterpret_cast<const float4*>(b1 + 4 * qg);
    const float4 thv = *reinterpret_cast<const float4*>(theta + 4 * qg);
    const float4 hv = (kq == 0) ? accA : accB;
    const int row = rowA + kq;
    float4 zv;
    zv.x = __cosf(fmaxf(hv.x + b1v.x, 0.f) + thv.x);
    zv.y = __cosf(fmaxf(hv.y + b1v.y, 0.f) + thv.y);
    zv.z = __cosf(fmaxf(hv.z + b1v.z, 0.f) + thv.z);
    zv.w = __cosf(fmaxf(hv.w + b1v.w, 0.f) + thv.w);
    *reinterpret_cast<float4*>(z + (size_t)row * QDIM + 4 * qg) = zv;
  }
}

// ===========================================================================
// Pass 2: out[r][d] = b2[d] + sum_q z[r][q] * W2[q][d]
// Thread owns cols 4t..4t+3; W2[16][4] in 64 VGPRs (constant-indexed array
// only — safe). Per row: 4 broadcast float4 z-loads (L2-hot) + 64 FMA + one
// coalesced float4 store. 32 rows/block so W2 is re-read from L2/L3 only
// 1024x (64 MB). Zero LDS, zero barriers.
// ===========================================================================
#define K2_TPB 256
#define K2_ROWS 32
#define K2_NBLOCKS (ROWS_TOTAL / K2_ROWS)  // 1024

__global__ __launch_bounds__(K2_TPB, 4)
void out_kernel(const float* __restrict__ z, const float* __restrict__ W2,
                const float* __restrict__ b2, float* __restrict__ out) {
  const int t = threadIdx.x;

  float4 w2r[QDIM];
#pragma unroll
  for (int q = 0; q < QDIM; ++q)
    w2r[q] = *reinterpret_cast<const float4*>(W2 + (size_t)q * DDIM + 4 * t);
  const float4 b2v = *reinterpret_cast<const float4*>(b2 + 4 * t);

  const int r0 = blockIdx.x * K2_ROWS;
  const float* zp = z + (size_t)r0 * QDIM;

#pragma unroll 4
  for (int i = 0; i < K2_ROWS; ++i) {
    const float4 z0 = *reinterpret_cast<const float4*>(zp + i * QDIM + 0);
    const float4 z1 = *reinterpret_cast<const float4*>(zp + i * QDIM + 4);
    const float4 z2 = *reinterpret_cast<const float4*>(zp + i * QDIM + 8);
    const float4 z3 = *reinterpret_cast<const float4*>(zp + i * QDIM + 12);
    float4 a = b2v;
#pragma unroll
    for (int j = 0; j < 4; ++j) {
      const float4 zv = (j == 0) ? z0 : (j == 1) ? z1 : (j == 2) ? z2 : z3;
#pragma unroll
      for (int c = 0; c < 4; ++c) {
        const float zs = (c == 0) ? zv.x : (c == 1) ? zv.y
                       : (c == 2) ? zv.z : zv.w;
        const float4 wv = w2r[4 * j + c];  // compile-time index
        a.x = fmaf(zs, wv.x, a.x);
        a.y = fmaf(zs, wv.y, a.y);
        a.z = fmaf(zs, wv.z, a.z);
        a.w = fmaf(zs, wv.w, a.w);
      }
    }
    *reinterpret_cast<float4*>(out + (size_t)(r0 + i) * DDIM + 4 * t) = a;
  }
}

// ===========================================================================
// Fallback: previous best fused kernel (used only if ws_size < 2 MB).
// ===========================================================================
#define TPB 512
#define RPB 16
#define R 4
#define NPH (RPB / R)
#define NBLOCKS (ROWS_TOTAL / RPB)

__global__ __launch_bounds__(TPB, 4)
void ffq_kernel(const float* __restrict__ x, const float* __restrict__ W1,
                const float* __restrict__ b1, const float* __restrict__ theta,
                const float* __restrict__ W2, const float* __restrict__ b2,
                float* __restrict__ out) {
  const int t    = threadIdx.x;
  const int lane = t & 63;
  const int wid  = t >> 6;
  const int qg   = t & 3;
  const int c    = t >> 2;
  const int q5   = lane & 15;
  const int r5   = lane >> 4;

  __shared__ __align__(16) float hw[2][16][R][QDIM];
  __shared__ __align__(16) float zs[8][R][QDIM];

  float w1r[8][4];
  {
    const float* p = W1 + (size_t)(8 * c) * QDIM + 4 * qg;
#pragma unroll
    for (int j = 0; j < 8; ++j) {
      float4 v = *reinterpret_cast<const float4*>(p + (size_t)j * QDIM);
      w1r[j][0] = v.x; w1r[j][1] = v.y; w1r[j][2] = v.z; w1r[j][3] = v.w;
    }
  }
  float w2r[QDIM][2];
#pragma unroll
  for (int q = 0; q < QDIM; ++q) {
    float2 v = *reinterpret_cast<const float2*>(W2 + (size_t)q * DDIM + 2 * t);
    w2r[q][0] = v.x; w2r[q][1] = v.y;
  }
  const float2 b2r = *reinterpret_cast<const float2*>(b2 + 2 * t);
  const float b1q = b1[q5];
  const float thq = theta[q5];

  const int row0 = blockIdx.x * RPB;

  float4 xa[R], xb[R];
  {
    const float* p = x + (size_t)row0 * DDIM + 8 * c;
#pragma unroll
    for (int r = 0; r < R; ++r) {
      xa[r] = *reinterpret_cast<const float4*>(p + (size_t)r * DDIM);
      xb[r] = *reinterpret_cast<const float4*>(p + (size_t)r * DDIM + 4);
    }
  }

  auto mm2_store = [&](int rowp) {
#pragma unroll
    for (int r = 0; r < R; ++r) {
      float o0 = b2r.x, o1 = b2r.y;
#pragma unroll
      for (int jb = 0; jb < 4; ++jb) {
        float4 zv = *reinterpret_cast<const float4*>(&zs[wid][r][4 * jb]);
        o0 = fmaf(zv.x, w2r[4 * jb + 0][0], o0);
        o1 = fmaf(zv.x, w2r[4 * jb + 0][1], o1);
        o0 = fmaf(zv.y, w2r[4 * jb + 1][0], o0);
        o1 = fmaf(zv.y, w2r[4 * jb + 1][1], o1);
        o0 = fmaf(zv.z, w2r[4 * jb + 2][0], o0);
        o1 = fmaf(zv.z, w2r[4 * jb + 2][1], o1);
        o0 = fmaf(zv.w, w2r[4 * jb + 3][0], o0);
        o1 = fmaf(zv.w, w2r[4 * jb + 3][1], o1);
      }
      *reinterpret_cast<float2*>(out + (size_t)(rowp + r) * DDIM + 2 * t) =
          make_float2(o0, o1);
    }
  };

  for (int ph = 0; ph < NPH; ++ph) {
    const int buf = ph & 1;

    float hp[R][4];
#pragma unroll
    for (int r = 0; r < R; ++r) {
      const float xv[8] = {xa[r].x, xa[r].y, xa[r].z, xa[r].w,
                           xb[r].x, xb[r].y, xb[r].z, xb[r].w};
      float h0 = 0.f, h1 = 0.f, h2 = 0.f, h3 = 0.f;
#pragma unroll
      for (int j = 0; j < 8; ++j) {
        h0 = fmaf(xv[j], w1r[j][0], h0);
        h1 = fmaf(xv[j], w1r[j][1], h1);
        h2 = fmaf(xv[j], w1r[j][2], h2);
        h3 = fmaf(xv[j], w1r[j][3], h3);
      }
      hp[r][0] = h0; hp[r][1] = h1; hp[r][2] = h2; hp[r][3] = h3;
    }

#pragma unroll
    for (int m = 4; m <= 16; m <<= 1)
#pragma unroll
      for (int r = 0; r < R; ++r)
#pragma unroll
        for (int qq = 0; qq < 4; ++qq)
          hp[r][qq] += __shfl_xor(hp[r][qq], m, 64);

    if ((lane & 28) == 0) {
      const int j = wid * 2 + (lane >> 5);
#pragma unroll
      for (int r = 0; r < R; ++r)
        *reinterpret_cast<float4*>(&hw[buf][j][r][4 * qg]) =
            make_float4(hp[r][0], hp[r][1], hp[r][2], hp[r][3]);
    }
    __syncthreads();

    if (ph + 1 < NPH) {
      const float* p = x + (size_t)(row0 + (ph + 1) * R) * DDIM + 8 * c;
#pragma unroll
      for (int r = 0; r < R; ++r) {
        xa[r] = *reinterpret_cast<const float4*>(p + (size_t)r * DDIM);
        xb[r] = *reinterpret_cast<const float4*>(p + (size_t)r * DDIM + 4);
      }
    }

    if (ph > 0) mm2_store(row0 + (ph - 1) * R);

    float s = 0.f;
#pragma unroll
    for (int j = 0; j < 16; ++j) s += hw[buf][j][r5][q5];
    s = fmaxf(s + b1q, 0.f) + thq;
    zs[wid][r5][q5] = __cosf(s);
  }

  __syncthreads();
  mm2_store(row0 + (NPH - 1) * R);
}

extern "C" void kernel_launch(void* const* d_in, const int* in_sizes, int n_in,
                              void* d_out, int out_size, void* d_ws, size_t ws_size,
                              hipStream_t stream) {
  const float* x     = (const float*)d_in[0];
  const float* W1    = (const float*)d_in[1];
  const float* b1    = (const float*)d_in[2];
  const float* theta = (const float*)d_in[3];
  const float* W2    = (const float*)d_in[4];
  const float* b2    = (const float*)d_in[5];
  float* out = (float*)d_out;

  const size_t z_bytes = (size_t)ROWS_TOTAL * QDIM * sizeof(float);  // 2 MiB
  if (ws_size >= z_bytes && d_ws != nullptr) {
    float* z = (float*)d_ws;
    qz_kernel<<<dim3(K1_NBLOCKS), dim3(K1_TPB), 0, stream>>>(x, W1, b1, theta, z);
    out_kernel<<<dim3(K2_NBLOCKS), dim3(K2_TPB), 0, stream>>>(z, W2, b2, out);
  } else {
    ffq_kernel<<<dim3(NBLOCKS), dim3(TPB), 0, stream>>>(x, W1, b1, theta, W2, b2, out);
  }
}

// Round 4
// 316.947 us; speedup vs baseline: 1.7326x; 1.5263x over previous
//
#include <hip/hip_runtime.h>
#include <math.h>

// Problem constants: B=8, S=4096, D=1024, Q=16  -> 32768 rows
#define ROWS_TOTAL 32768
#define DDIM 1024
#define QDIM 16

// ===========================================================================
// Pass 1: z[r][q] = cos(relu(x[r]·W1[:,q] + b1[q]) + theta[q])
//
// Lane layout (64 = 4 k-quarters x 4 row-pairs x 4 q-quads):
//   qg = lane&3        q = 4qg..4qg+3
//   rr = (lane>>2)&3   rows rowA=wv*8+2rr, rowB=rowA+1
//   kq = lane>>4       k-range [256*kq, 256*kq+256)
// Each lane: 2 rows x 4 q x 256 k serial FMA. k-quarters merged by
// shfl_xor(16/32) butterfly. Zero LDS, zero barriers, all state in NAMED
// registers. NOTE: no min-occupancy in __launch_bounds__ — R2/R3 showed
// that (256,4) caps the allocator at 64 VGPRs (8-wave budget) and this
// kernel needs ~80, so the overflow spilled to scratch every iteration.
// ===========================================================================
#define K1_TPB 256
#define K1_NBLOCKS (ROWS_TOTAL / 8 / (K1_TPB / 64))  // 1024

__global__ __launch_bounds__(K1_TPB)
void qz_kernel(const float* __restrict__ x, const float* __restrict__ W1,
               const float* __restrict__ b1, const float* __restrict__ theta,
               float* __restrict__ z) {
  const int lane = threadIdx.x & 63;
  const int wv = blockIdx.x * (K1_TPB / 64) + (threadIdx.x >> 6);
  const int qg = lane & 3;
  const int rr = (lane >> 2) & 3;
  const int kq = lane >> 4;
  const int rowA = wv * 8 + rr * 2;

  const float* xpA = x + (size_t)rowA * DDIM + kq * 256;
  const float* xpB = xpA + DDIM;  // rowA+1
  const float* wp = W1 + (size_t)(kq * 256) * QDIM + 4 * qg;

  float4 accA = make_float4(0.f, 0.f, 0.f, 0.f);
  float4 accB = make_float4(0.f, 0.f, 0.f, 0.f);

  // acc.c += xv.j * wj.c  (j = k-offset, c = q-offset) — 16 FMA per call.
  auto fma16 = [](float4& a, const float4 xv, const float4 w0, const float4 w1,
                  const float4 w2, const float4 w3) {
    a.x = fmaf(xv.x, w0.x, a.x); a.y = fmaf(xv.x, w0.y, a.y);
    a.z = fmaf(xv.x, w0.z, a.z); a.w = fmaf(xv.x, w0.w, a.w);
    a.x = fmaf(xv.y, w1.x, a.x); a.y = fmaf(xv.y, w1.y, a.y);
    a.z = fmaf(xv.y, w1.z, a.z); a.w = fmaf(xv.y, w1.w, a.w);
    a.x = fmaf(xv.z, w2.x, a.x); a.y = fmaf(xv.z, w2.y, a.y);
    a.z = fmaf(xv.z, w2.z, a.z); a.w = fmaf(xv.z, w2.w, a.w);
    a.x = fmaf(xv.w, w3.x, a.x); a.y = fmaf(xv.w, w3.y, a.y);
    a.z = fmaf(xv.w, w3.z, a.z); a.w = fmaf(xv.w, w3.w, a.w);
  };

  // prologue: x double-buffered (xa=even stage, xb=odd stage), W1 for stage 0
  float4 xaA = *reinterpret_cast<const float4*>(xpA);
  float4 xaB = *reinterpret_cast<const float4*>(xpB);
  float4 xbA = *reinterpret_cast<const float4*>(xpA + 4);
  float4 xbB = *reinterpret_cast<const float4*>(xpB + 4);
  float4 wa0 = *reinterpret_cast<const float4*>(wp + 0 * QDIM);
  float4 wa1 = *reinterpret_cast<const float4*>(wp + 1 * QDIM);
  float4 wa2 = *reinterpret_cast<const float4*>(wp + 2 * QDIM);
  float4 wa3 = *reinterpret_cast<const float4*>(wp + 3 * QDIM);

#pragma unroll 1
  for (int s = 0; s < 64; s += 2) {
    // W for odd stage s+1 (issued before even-stage FMAs -> latency hidden)
    const float* pwb = wp + (size_t)(4 * (s + 1)) * QDIM;
    const float4 wb0 = *reinterpret_cast<const float4*>(pwb + 0 * QDIM);
    const float4 wb1 = *reinterpret_cast<const float4*>(pwb + 1 * QDIM);
    const float4 wb2 = *reinterpret_cast<const float4*>(pwb + 2 * QDIM);
    const float4 wb3 = *reinterpret_cast<const float4*>(pwb + 3 * QDIM);

    // even stage s: consume xa / wa
    fma16(accA, xaA, wa0, wa1, wa2, wa3);
    fma16(accB, xaB, wa0, wa1, wa2, wa3);

    // prefetch x for stage s+2 (clamped on last iter; redundant re-read ok)
    const int sp = (s + 2 < 64) ? (s + 2) : 0;
    xaA = *reinterpret_cast<const float4*>(xpA + 4 * sp);
    xaB = *reinterpret_cast<const float4*>(xpB + 4 * sp);

    // W for even stage s+2
    const float* pwa = wp + (size_t)(4 * sp) * QDIM;
    wa0 = *reinterpret_cast<const float4*>(pwa + 0 * QDIM);
    wa1 = *reinterpret_cast<const float4*>(pwa + 1 * QDIM);
    wa2 = *reinterpret_cast<const float4*>(pwa + 2 * QDIM);
    wa3 = *reinterpret_cast<const float4*>(pwa + 3 * QDIM);

    // odd stage s+1: consume xb / wb
    fma16(accA, xbA, wb0, wb1, wb2, wb3);
    fma16(accB, xbB, wb0, wb1, wb2, wb3);

    // prefetch x for stage s+3
    const int sq = (s + 3 < 64) ? (s + 3) : 1;
    xbA = *reinterpret_cast<const float4*>(xpA + 4 * sq);
    xbB = *reinterpret_cast<const float4*>(xpB + 4 * sq);
  }

  // merge the 4 k-quarters: butterfly over lane bits 4 and 5
  auto red = [](float v) {
    v += __shfl_xor(v, 16);
    v += __shfl_xor(v, 32);
    return v;
  };
  accA.x = red(accA.x); accA.y = red(accA.y);
  accA.z = red(accA.z); accA.w = red(accA.w);
  accB.x = red(accB.x); accB.y = red(accB.y);
  accB.z = red(accB.z); accB.w = red(accB.w);

  // kq==0 lanes store rowA's quad, kq==1 lanes store rowB's quad
  if (kq < 2) {
    const float4 b1v = *reinterpret_cast<const float4*>(b1 + 4 * qg);
    const float4 thv = *reinterpret_cast<const float4*>(theta + 4 * qg);
    const float4 hv = (kq == 0) ? accA : accB;
    const int row = rowA + kq;
    float4 zv;
    zv.x = __cosf(fmaxf(hv.x + b1v.x, 0.f) + thv.x);
    zv.y = __cosf(fmaxf(hv.y + b1v.y, 0.f) + thv.y);
    zv.z = __cosf(fmaxf(hv.z + b1v.z, 0.f) + thv.z);
    zv.w = __cosf(fmaxf(hv.w + b1v.w, 0.f) + thv.w);
    *reinterpret_cast<float4*>(z + (size_t)row * QDIM + 4 * qg) = zv;
  }
}

// ===========================================================================
// Pass 2: out[r][d] = b2[d] + sum_q z[r][q] * W2[q][d]
// Thread owns cols 4t..4t+3; W2 column-block in 16 NAMED float4s (64 VGPRs
// that the R3 array version spilled: VGPR_Count=64 cap + array SROA failure
// gave 270 MB/270 MB of symmetric scratch FETCH/WRITE). No arrays, no
// min-occupancy cap. Per row: 4 broadcast float4 z-loads (L2-hot) + 64 FMA
// + one coalesced float4 store. Zero LDS, zero barriers.
// ===========================================================================
#define K2_TPB 256
#define K2_ROWS 32
#define K2_NBLOCKS (ROWS_TOTAL / K2_ROWS)  // 1024

__global__ __launch_bounds__(K2_TPB)
void out_kernel(const float* __restrict__ z, const float* __restrict__ W2,
                const float* __restrict__ b2, float* __restrict__ out) {
  const int t = threadIdx.x;
  const float* wb = W2 + 4 * t;

  const float4 w00 = *reinterpret_cast<const float4*>(wb + 0 * DDIM);
  const float4 w01 = *reinterpret_cast<const float4*>(wb + 1 * DDIM);
  const float4 w02 = *reinterpret_cast<const float4*>(wb + 2 * DDIM);
  const float4 w03 = *reinterpret_cast<const float4*>(wb + 3 * DDIM);
  const float4 w04 = *reinterpret_cast<const float4*>(wb + 4 * DDIM);
  const float4 w05 = *reinterpret_cast<const float4*>(wb + 5 * DDIM);
  const float4 w06 = *reinterpret_cast<const float4*>(wb + 6 * DDIM);
  const float4 w07 = *reinterpret_cast<const float4*>(wb + 7 * DDIM);
  const float4 w08 = *reinterpret_cast<const float4*>(wb + 8 * DDIM);
  const float4 w09 = *reinterpret_cast<const float4*>(wb + 9 * DDIM);
  const float4 w10 = *reinterpret_cast<const float4*>(wb + 10 * DDIM);
  const float4 w11 = *reinterpret_cast<const float4*>(wb + 11 * DDIM);
  const float4 w12 = *reinterpret_cast<const float4*>(wb + 12 * DDIM);
  const float4 w13 = *reinterpret_cast<const float4*>(wb + 13 * DDIM);
  const float4 w14 = *reinterpret_cast<const float4*>(wb + 14 * DDIM);
  const float4 w15 = *reinterpret_cast<const float4*>(wb + 15 * DDIM);
  const float4 b2v = *reinterpret_cast<const float4*>(b2 + 4 * t);

  // a += zq.{x,y,z,w} * wA..wD  (16 FMAs: one z-quad against 4 W2 rows)
  auto fmaq = [](float4& a, const float4 zq, const float4 wA, const float4 wB,
                 const float4 wC, const float4 wD) {
    a.x = fmaf(zq.x, wA.x, a.x); a.y = fmaf(zq.x, wA.y, a.y);
    a.z = fmaf(zq.x, wA.z, a.z); a.w = fmaf(zq.x, wA.w, a.w);
    a.x = fmaf(zq.y, wB.x, a.x); a.y = fmaf(zq.y, wB.y, a.y);
    a.z = fmaf(zq.y, wB.z, a.z); a.w = fmaf(zq.y, wB.w, a.w);
    a.x = fmaf(zq.z, wC.x, a.x); a.y = fmaf(zq.z, wC.y, a.y);
    a.z = fmaf(zq.z, wC.z, a.z); a.w = fmaf(zq.z, wC.w, a.w);
    a.x = fmaf(zq.w, wD.x, a.x); a.y = fmaf(zq.w, wD.y, a.y);
    a.z = fmaf(zq.w, wD.z, a.z); a.w = fmaf(zq.w, wD.w, a.w);
  };

  const int r0 = blockIdx.x * K2_ROWS;
  const float* zp = z + (size_t)r0 * QDIM;
  float* op = out + (size_t)r0 * DDIM + 4 * t;

#pragma unroll 2
  for (int i = 0; i < K2_ROWS; ++i) {
    const float4 z0 = *reinterpret_cast<const float4*>(zp + i * QDIM + 0);
    const float4 z1 = *reinterpret_cast<const float4*>(zp + i * QDIM + 4);
    const float4 z2 = *reinterpret_cast<const float4*>(zp + i * QDIM + 8);
    const float4 z3 = *reinterpret_cast<const float4*>(zp + i * QDIM + 12);
    float4 a = b2v;
    fmaq(a, z0, w00, w01, w02, w03);
    fmaq(a, z1, w04, w05, w06, w07);
    fmaq(a, z2, w08, w09, w10, w11);
    fmaq(a, z3, w12, w13, w14, w15);
    *reinterpret_cast<float4*>(op + (size_t)i * DDIM) = a;
  }
}

// ===========================================================================
// Fallback: previous best fused kernel (used only if ws_size < 2 MB).
// ===========================================================================
#define TPB 512
#define RPB 16
#define R 4
#define NPH (RPB / R)
#define NBLOCKS (ROWS_TOTAL / RPB)

__global__ __launch_bounds__(TPB, 4)
void ffq_kernel(const float* __restrict__ x, const float* __restrict__ W1,
                const float* __restrict__ b1, const float* __restrict__ theta,
                const float* __restrict__ W2, const float* __restrict__ b2,
                float* __restrict__ out) {
  const int t    = threadIdx.x;
  const int lane = t & 63;
  const int wid  = t >> 6;
  const int qg   = t & 3;
  const int c    = t >> 2;
  const int q5   = lane & 15;
  const int r5   = lane >> 4;

  __shared__ __align__(16) float hw[2][16][R][QDIM];
  __shared__ __align__(16) float zs[8][R][QDIM];

  float w1r[8][4];
  {
    const float* p = W1 + (size_t)(8 * c) * QDIM + 4 * qg;
#pragma unroll
    for (int j = 0; j < 8; ++j) {
      float4 v = *reinterpret_cast<const float4*>(p + (size_t)j * QDIM);
      w1r[j][0] = v.x; w1r[j][1] = v.y; w1r[j][2] = v.z; w1r[j][3] = v.w;
    }
  }
  float w2r[QDIM][2];
#pragma unroll
  for (int q = 0; q < QDIM; ++q) {
    float2 v = *reinterpret_cast<const float2*>(W2 + (size_t)q * DDIM + 2 * t);
    w2r[q][0] = v.x; w2r[q][1] = v.y;
  }
  const float2 b2r = *reinterpret_cast<const float2*>(b2 + 2 * t);
  const float b1q = b1[q5];
  const float thq = theta[q5];

  const int row0 = blockIdx.x * RPB;

  float4 xa[R], xb[R];
  {
    const float* p = x + (size_t)row0 * DDIM + 8 * c;
#pragma unroll
    for (int r = 0; r < R; ++r) {
      xa[r] = *reinterpret_cast<const float4*>(p + (size_t)r * DDIM);
      xb[r] = *reinterpret_cast<const float4*>(p + (size_t)r * DDIM + 4);
    }
  }

  auto mm2_store = [&](int rowp) {
#pragma unroll
    for (int r = 0; r < R; ++r) {
      float o0 = b2r.x, o1 = b2r.y;
#pragma unroll
      for (int jb = 0; jb < 4; ++jb) {
        float4 zv = *reinterpret_cast<const float4*>(&zs[wid][r][4 * jb]);
        o0 = fmaf(zv.x, w2r[4 * jb + 0][0], o0);
        o1 = fmaf(zv.x, w2r[4 * jb + 0][1], o1);
        o0 = fmaf(zv.y, w2r[4 * jb + 1][0], o0);
        o1 = fmaf(zv.y, w2r[4 * jb + 1][1], o1);
        o0 = fmaf(zv.z, w2r[4 * jb + 2][0], o0);
        o1 = fmaf(zv.z, w2r[4 * jb + 2][1], o1);
        o0 = fmaf(zv.w, w2r[4 * jb + 3][0], o0);
        o1 = fmaf(zv.w, w2r[4 * jb + 3][1], o1);
      }
      *reinterpret_cast<float2*>(out + (size_t)(rowp + r) * DDIM + 2 * t) =
          make_float2(o0, o1);
    }
  };

  for (int ph = 0; ph < NPH; ++ph) {
    const int buf = ph & 1;

    float hp[R][4];
#pragma unroll
    for (int r = 0; r < R; ++r) {
      const float xv[8] = {xa[r].x, xa[r].y, xa[r].z, xa[r].w,
                           xb[r].x, xb[r].y, xb[r].z, xb[r].w};
      float h0 = 0.f, h1 = 0.f, h2 = 0.f, h3 = 0.f;
#pragma unroll
      for (int j = 0; j < 8; ++j) {
        h0 = fmaf(xv[j], w1r[j][0], h0);
        h1 = fmaf(xv[j], w1r[j][1], h1);
        h2 = fmaf(xv[j], w1r[j][2], h2);
        h3 = fmaf(xv[j], w1r[j][3], h3);
      }
      hp[r][0] = h0; hp[r][1] = h1; hp[r][2] = h2; hp[r][3] = h3;
    }

#pragma unroll
    for (int m = 4; m <= 16; m <<= 1)
#pragma unroll
      for (int r = 0; r < R; ++r)
#pragma unroll
        for (int qq = 0; qq < 4; ++qq)
          hp[r][qq] += __shfl_xor(hp[r][qq], m, 64);

    if ((lane & 28) == 0) {
      const int j = wid * 2 + (lane >> 5);
#pragma unroll
      for (int r = 0; r < R; ++r)
        *reinterpret_cast<float4*>(&hw[buf][j][r][4 * qg]) =
            make_float4(hp[r][0], hp[r][1], hp[r][2], hp[r][3]);
    }
    __syncthreads();

    if (ph + 1 < NPH) {
      const float* p = x + (size_t)(row0 + (ph + 1) * R) * DDIM + 8 * c;
#pragma unroll
      for (int r = 0; r < R; ++r) {
        xa[r] = *reinterpret_cast<const float4*>(p + (size_t)r * DDIM);
        xb[r] = *reinterpret_cast<const float4*>(p + (size_t)r * DDIM + 4);
      }
    }

    if (ph > 0) mm2_store(row0 + (ph - 1) * R);

    float s = 0.f;
#pragma unroll
    for (int j = 0; j < 16; ++j) s += hw[buf][j][r5][q5];
    s = fmaxf(s + b1q, 0.f) + thq;
    zs[wid][r5][q5] = __cosf(s);
  }

  __syncthreads();
  mm2_store(row0 + (NPH - 1) * R);
}

extern "C" void kernel_launch(void* const* d_in, const int* in_sizes, int n_in,
                              void* d_out, int out_size, void* d_ws, size_t ws_size,
                              hipStream_t stream) {
  const float* x     = (const float*)d_in[0];
  const float* W1    = (const float*)d_in[1];
  const float* b1    = (const float*)d_in[2];
  const float* theta = (const float*)d_in[3];
  const float* W2    = (const float*)d_in[4];
  const float* b2    = (const float*)d_in[5];
  float* out = (float*)d_out;

  const size_t z_bytes = (size_t)ROWS_TOTAL * QDIM * sizeof(float);  // 2 MiB
  if (ws_size >= z_bytes && d_ws != nullptr) {
    float* z = (float*)d_ws;
    qz_kernel<<<dim3(K1_NBLOCKS), dim3(K1_TPB), 0, stream>>>(x, W1, b1, theta, z);
    out_kernel<<<dim3(K2_NBLOCKS), dim3(K2_TPB), 0, stream>>>(z, W2, b2, out);
  } else {
    ffq_kernel<<<dim3(NBLOCKS), dim3(TPB), 0, stream>>>(x, W1, b1, theta, W2, b2, out);
  }
}